// Round 1
// baseline (1249.782 us; speedup 1.0000x reference)
//
#include <hip/hip_runtime.h>

#define N_NODES 50000
#define N_EDGES 625000
#define DIM 128

// ---------------------------------------------------------------------------
// Fused GEMM + bias + relu:  out[i][j] = relu(sum_k a[i][k] * W[j][k] + b[j])
// FUSE=1: a[i][k] = 1 + eps*A[i][k] + nbuf[i][k]   (GIN combine, fused)
// Block: 256 threads, tile = 64 nodes x 128 cols.
// W staged in exactly 64KiB LDS, layout [k][j] with float4-granular XOR
// swizzle (jg ^ (k&31)) -> inner-loop reads are the contiguous conflict-free
// pattern; staging writes are ~4-way (one-time).
// A rows read direct from global: lanes 0..31 of a wave share the address
// (broadcast), L1-resident.
// ---------------------------------------------------------------------------
template <int FUSE>
__global__ __launch_bounds__(256) void gemm_relu_k(
    const float* __restrict__ A,
    const float* __restrict__ nbuf,
    const float* __restrict__ eps_p,
    const float* __restrict__ W,      // [128][128] row-major (out, in)
    const float* __restrict__ bias,   // [128]
    float* __restrict__ out)
{
    __shared__ float w_lds[DIM * DIM];   // 64 KiB, swizzled [k][j]

    const int t = threadIdx.x;
    const int node0 = blockIdx.x * 64;

    // Stage W (scalar, coalesced global reads; swizzled LDS writes)
    for (int it = 0; it < 64; ++it) {
        int f = it * 256 + t;          // f = j*128 + k
        int j = f >> 7;
        int k = f & 127;
        int jg = j >> 2;
        int idx = k * DIM + ((((jg ^ (k & 31)) << 2) | (j & 3)));
        w_lds[idx] = W[f];
    }
    __syncthreads();

    float eps = 0.0f;
    if (FUSE) eps = eps_p[0];

    const int i0 = (t >> 5) * 8;       // 8 nodes per thread
    const int jg = t & 31;             // col group: cols 4*jg .. 4*jg+3
    const int jc = jg << 2;

    int rows[8];
#pragma unroll
    for (int ii = 0; ii < 8; ++ii) {
        int nd = node0 + i0 + ii;
        rows[ii] = (nd < N_NODES) ? nd : (N_NODES - 1);  // clamp for safe loads
    }

    float acc[8][4];
#pragma unroll
    for (int ii = 0; ii < 8; ++ii)
#pragma unroll
        for (int jj = 0; jj < 4; ++jj) acc[ii][jj] = 0.0f;

    for (int k = 0; k < DIM; k += 4) {
        float wk[4][4];
#pragma unroll
        for (int kk = 0; kk < 4; ++kk) {
            int kr = k + kk;
            const float4 wv = *(const float4*)&w_lds[kr * DIM + ((jg ^ (kr & 31)) << 2)];
            wk[kk][0] = wv.x; wk[kk][1] = wv.y; wk[kk][2] = wv.z; wk[kk][3] = wv.w;
        }
        float av[8][4];
#pragma unroll
        for (int ii = 0; ii < 8; ++ii) {
            const float4 a4 = *(const float4*)&A[(size_t)rows[ii] * DIM + k];
            av[ii][0] = a4.x; av[ii][1] = a4.y; av[ii][2] = a4.z; av[ii][3] = a4.w;
        }
        if (FUSE) {
#pragma unroll
            for (int ii = 0; ii < 8; ++ii) {
                const float4 n4 = *(const float4*)&nbuf[(size_t)rows[ii] * DIM + k];
                av[ii][0] = 1.0f + eps * av[ii][0] + n4.x;
                av[ii][1] = 1.0f + eps * av[ii][1] + n4.y;
                av[ii][2] = 1.0f + eps * av[ii][2] + n4.z;
                av[ii][3] = 1.0f + eps * av[ii][3] + n4.w;
            }
        }
#pragma unroll
        for (int ii = 0; ii < 8; ++ii)
#pragma unroll
            for (int kk = 0; kk < 4; ++kk)
#pragma unroll
                for (int jj = 0; jj < 4; ++jj)
                    acc[ii][jj] += av[ii][kk] * wk[kk][jj];
    }

    const float4 bv = *(const float4*)&bias[jc];
#pragma unroll
    for (int ii = 0; ii < 8; ++ii) {
        int nd = node0 + i0 + ii;
        if (nd < N_NODES) {
            float4 o;
            o.x = fmaxf(acc[ii][0] + bv.x, 0.0f);
            o.y = fmaxf(acc[ii][1] + bv.y, 0.0f);
            o.z = fmaxf(acc[ii][2] + bv.z, 0.0f);
            o.w = fmaxf(acc[ii][3] + bv.w, 0.0f);
            *(float4*)&out[(size_t)nd * DIM + jc] = o;
        }
    }
}

// ---------------------------------------------------------------------------
// Edge scatter-sum: n[dst[e]][c] += h[src[e]][c]
// One thread per (edge, 4 channels): float4 gather + 4 fp32 global atomics.
// ---------------------------------------------------------------------------
__global__ __launch_bounds__(256) void scatter_k(
    const float* __restrict__ h,
    const int* __restrict__ src,
    const int* __restrict__ dst,
    float* __restrict__ nbuf)
{
    int idx = blockIdx.x * 256 + threadIdx.x;   // < 20M, fits int
    int e = idx >> 5;
    int c = (idx & 31) << 2;
    if (e >= N_EDGES) return;
    int s = src[e];
    int d = dst[e];
    const float4 v = *(const float4*)&h[(size_t)s * DIM + c];
    float* np = nbuf + (size_t)d * DIM + c;
    atomicAdd(np + 0, v.x);
    atomicAdd(np + 1, v.y);
    atomicAdd(np + 2, v.z);
    atomicAdd(np + 3, v.w);
}

extern "C" void kernel_launch(void* const* d_in, const int* in_sizes, int n_in,
                              void* d_out, int out_size, void* d_ws, size_t ws_size,
                              hipStream_t stream) {
    const float* feats = (const float*)d_in[0];
    const int*   src   = (const int*)d_in[1];
    const int*   dst   = (const int*)d_in[2];
    const float* W_f   = (const float*)d_in[3];
    const float* b_f   = (const float*)d_in[4];
    const float* W_phy = (const float*)d_in[5];
    const float* b_phy = (const float*)d_in[6];
    const float* eps   = (const float*)d_in[7];
    float* out = (float*)d_out;

    float* h    = (float*)d_ws;                         // 50000*128 fp32 = 25.6 MB
    float* nbuf = h + (size_t)N_NODES * DIM;            // another 25.6 MB

    // zero the aggregation buffer (ws is poisoned before every call)
    hipMemsetAsync(nbuf, 0, (size_t)N_NODES * DIM * sizeof(float), stream);

    const int gblocks = (N_NODES + 63) / 64;            // 782

    gemm_relu_k<0><<<gblocks, 256, 0, stream>>>(feats, nullptr, nullptr, W_f, b_f, h);

    const int sblocks = (N_EDGES * 32) / 256;           // 78125 exactly
    scatter_k<<<sblocks, 256, 0, stream>>>(h, src, dst, nbuf);

    gemm_relu_k<1><<<gblocks, 256, 0, stream>>>(h, nbuf, eps, W_phy, b_phy, out);
}

// Round 2
// 311.033 us; speedup vs baseline: 4.0182x; 4.0182x over previous
//
#include <hip/hip_runtime.h>

#define N_NODES 50000
#define N_EDGES 625000
#define DIM 128

// ===========================================================================
// GEMM + bias + relu (unchanged from R1):
//   out[i][j] = relu(sum_k a[i][k] * W[j][k] + b[j])
// FUSE=1: a[i][k] = 1 + eps*A[i][k] + nbuf[i][k]
// ===========================================================================
template <int FUSE>
__global__ __launch_bounds__(256) void gemm_relu_k(
    const float* __restrict__ A,
    const float* __restrict__ nbuf,
    const float* __restrict__ eps_p,
    const float* __restrict__ W,
    const float* __restrict__ bias,
    float* __restrict__ out)
{
    __shared__ float w_lds[DIM * DIM];   // 64 KiB, swizzled [k][j]

    const int t = threadIdx.x;
    const int node0 = blockIdx.x * 64;

    for (int it = 0; it < 64; ++it) {
        int f = it * 256 + t;
        int j = f >> 7;
        int k = f & 127;
        int jg = j >> 2;
        int idx = k * DIM + ((((jg ^ (k & 31)) << 2) | (j & 3)));
        w_lds[idx] = W[f];
    }
    __syncthreads();

    float eps = 0.0f;
    if (FUSE) eps = eps_p[0];

    const int i0 = (t >> 5) * 8;
    const int jg = t & 31;
    const int jc = jg << 2;

    int rows[8];
#pragma unroll
    for (int ii = 0; ii < 8; ++ii) {
        int nd = node0 + i0 + ii;
        rows[ii] = (nd < N_NODES) ? nd : (N_NODES - 1);
    }

    float acc[8][4];
#pragma unroll
    for (int ii = 0; ii < 8; ++ii)
#pragma unroll
        for (int jj = 0; jj < 4; ++jj) acc[ii][jj] = 0.0f;

    for (int k = 0; k < DIM; k += 4) {
        float wk[4][4];
#pragma unroll
        for (int kk = 0; kk < 4; ++kk) {
            int kr = k + kk;
            const float4 wv = *(const float4*)&w_lds[kr * DIM + ((jg ^ (kr & 31)) << 2)];
            wk[kk][0] = wv.x; wk[kk][1] = wv.y; wk[kk][2] = wv.z; wk[kk][3] = wv.w;
        }
        float av[8][4];
#pragma unroll
        for (int ii = 0; ii < 8; ++ii) {
            const float4 a4 = *(const float4*)&A[(size_t)rows[ii] * DIM + k];
            av[ii][0] = a4.x; av[ii][1] = a4.y; av[ii][2] = a4.z; av[ii][3] = a4.w;
        }
        if (FUSE) {
#pragma unroll
            for (int ii = 0; ii < 8; ++ii) {
                const float4 n4 = *(const float4*)&nbuf[(size_t)rows[ii] * DIM + k];
                av[ii][0] = 1.0f + eps * av[ii][0] + n4.x;
                av[ii][1] = 1.0f + eps * av[ii][1] + n4.y;
                av[ii][2] = 1.0f + eps * av[ii][2] + n4.z;
                av[ii][3] = 1.0f + eps * av[ii][3] + n4.w;
            }
        }
#pragma unroll
        for (int ii = 0; ii < 8; ++ii)
#pragma unroll
            for (int kk = 0; kk < 4; ++kk)
#pragma unroll
                for (int jj = 0; jj < 4; ++jj)
                    acc[ii][jj] += av[ii][kk] * wk[kk][jj];
    }

    const float4 bv = *(const float4*)&bias[jc];
#pragma unroll
    for (int ii = 0; ii < 8; ++ii) {
        int nd = node0 + i0 + ii;
        if (nd < N_NODES) {
            float4 o;
            o.x = fmaxf(acc[ii][0] + bv.x, 0.0f);
            o.y = fmaxf(acc[ii][1] + bv.y, 0.0f);
            o.z = fmaxf(acc[ii][2] + bv.z, 0.0f);
            o.w = fmaxf(acc[ii][3] + bv.w, 0.0f);
            *(float4*)&out[(size_t)nd * DIM + jc] = o;
        }
    }
}

// ===========================================================================
// CSR build: histogram -> exclusive scan -> fill (offsets become segment ends)
// ===========================================================================
__global__ __launch_bounds__(256) void hist_k(
    const int* __restrict__ dst, int* __restrict__ deg)
{
    int e = blockIdx.x * 256 + threadIdx.x;
    if (e < N_EDGES) atomicAdd(&deg[dst[e]], 1);
}

// 49 blocks x 256 threads, 1024 elements/block; in-place block-local
// exclusive scan of deg[]; block totals -> blocksums[].
__global__ __launch_bounds__(256) void scan_blocks_k(
    int* __restrict__ deg, int* __restrict__ blocksums)
{
    __shared__ int s[256];
    const int t = threadIdx.x;
    const int base = blockIdx.x * 1024 + t * 4;

    int v[4] = {0, 0, 0, 0};
    if (base + 3 < N_NODES) {
        int4 q = *(const int4*)&deg[base];
        v[0] = q.x; v[1] = q.y; v[2] = q.z; v[3] = q.w;
    } else {
#pragma unroll
        for (int j = 0; j < 4; ++j)
            if (base + j < N_NODES) v[j] = deg[base + j];
    }
    int sum = v[0] + v[1] + v[2] + v[3];
    s[t] = sum;
    __syncthreads();
    // Hillis-Steele inclusive scan over 256 thread sums
    for (int off = 1; off < 256; off <<= 1) {
        int x = (t >= off) ? s[t - off] : 0;
        __syncthreads();
        s[t] += x;
        __syncthreads();
    }
    if (t == 255) blocksums[blockIdx.x] = s[255];
    int run = s[t] - sum;   // exclusive prefix of this thread's chunk
#pragma unroll
    for (int j = 0; j < 4; ++j) {
        int ex = run;
        run += v[j];
        if (base + j < N_NODES) deg[base + j] = ex;
    }
}

// Add cross-block carry (sum of blocksums[0..bid-1]) to each element.
__global__ __launch_bounds__(256) void scan_add_k(
    int* __restrict__ deg, const int* __restrict__ blocksums, int nblocks)
{
    __shared__ int carry_s;
    const int t = threadIdx.x;
    if (t < 64) {
        int v = (t < blockIdx.x && t < nblocks) ? blocksums[t] : 0;
#pragma unroll
        for (int off = 32; off > 0; off >>= 1) v += __shfl_down(v, off, 64);
        if (t == 0) carry_s = v;
    }
    __syncthreads();
    const int carry = carry_s;
    if (carry == 0) return;
    const int base = blockIdx.x * 1024 + t * 4;
#pragma unroll
    for (int j = 0; j < 4; ++j)
        if (base + j < N_NODES) deg[base + j] += carry;
}

// Scatter edge sources into CSR order. After this kernel, deg[d] holds the
// END offset of segment d (start is deg[d-1], or 0 for d==0).
__global__ __launch_bounds__(256) void fill_k(
    const int* __restrict__ src, const int* __restrict__ dst,
    int* __restrict__ deg, int* __restrict__ edge_src)
{
    int e = blockIdx.x * 256 + threadIdx.x;
    if (e < N_EDGES) {
        int d = dst[e];
        int p = atomicAdd(&deg[d], 1);
        edge_src[p] = src[e];
    }
}

// ===========================================================================
// Aggregate: one wave per node. Half-wave (32 lanes, float4 = 128 ch) per
// edge, two edges in flight per iteration, cross-half shfl reduce at end.
// No atomics; every node written exactly once (deg-0 nodes write zeros).
// ===========================================================================
__global__ __launch_bounds__(256) void aggregate_k(
    const float* __restrict__ h, const int* __restrict__ deg,
    const int* __restrict__ edge_src, float* __restrict__ nbuf)
{
    const int t = threadIdx.x;
    const int node = blockIdx.x * 4 + (t >> 6);
    if (node >= N_NODES) return;
    const int lane = t & 63;
    const int half = lane >> 5;
    const int cl = lane & 31;          // float4 group: channels 4*cl..4*cl+3

    const int start = node ? deg[node - 1] : 0;
    const int end = deg[node];

    float4 acc = make_float4(0.f, 0.f, 0.f, 0.f);
    for (int ei = start + half; ei < end; ei += 2) {
        int s = edge_src[ei];
        const float4 v = *(const float4*)&h[(size_t)s * DIM + (cl << 2)];
        acc.x += v.x; acc.y += v.y; acc.z += v.z; acc.w += v.w;
    }
    // combine the two halves
    acc.x += __shfl_down(acc.x, 32, 64);
    acc.y += __shfl_down(acc.y, 32, 64);
    acc.z += __shfl_down(acc.z, 32, 64);
    acc.w += __shfl_down(acc.w, 32, 64);
    if (half == 0)
        *(float4*)&nbuf[(size_t)node * DIM + (cl << 2)] = acc;
}

// Fallback (R1 path) if ws is too small for the CSR buffers.
__global__ __launch_bounds__(256) void scatter_k(
    const float* __restrict__ h, const int* __restrict__ src,
    const int* __restrict__ dst, float* __restrict__ nbuf)
{
    int idx = blockIdx.x * 256 + threadIdx.x;
    int e = idx >> 5;
    int c = (idx & 31) << 2;
    if (e >= N_EDGES) return;
    int s = src[e];
    int d = dst[e];
    const float4 v = *(const float4*)&h[(size_t)s * DIM + c];
    float* np = nbuf + (size_t)d * DIM + c;
    atomicAdd(np + 0, v.x);
    atomicAdd(np + 1, v.y);
    atomicAdd(np + 2, v.z);
    atomicAdd(np + 3, v.w);
}

extern "C" void kernel_launch(void* const* d_in, const int* in_sizes, int n_in,
                              void* d_out, int out_size, void* d_ws, size_t ws_size,
                              hipStream_t stream) {
    const float* feats = (const float*)d_in[0];
    const int*   src   = (const int*)d_in[1];
    const int*   dst   = (const int*)d_in[2];
    const float* W_f   = (const float*)d_in[3];
    const float* b_f   = (const float*)d_in[4];
    const float* W_phy = (const float*)d_in[5];
    const float* b_phy = (const float*)d_in[6];
    const float* eps   = (const float*)d_in[7];
    float* out = (float*)d_out;

    const size_t HN = (size_t)N_NODES * DIM;            // 6.4M floats
    float* h    = (float*)d_ws;                         // 25.6 MB
    float* nbuf = h + HN;                               // 25.6 MB
    int* edge_src = (int*)(nbuf + HN);                  // 2.5 MB
    int* deg      = edge_src + N_EDGES;                 // 200 KB
    int* blocksums = deg + N_NODES;                     // 196 B

    const size_t need_csr = (size_t)(blocksums + 64) - (size_t)d_ws;
    const int gblocks = (N_NODES + 63) / 64;            // 782

    gemm_relu_k<0><<<gblocks, 256, 0, stream>>>(feats, nullptr, nullptr, W_f, b_f, h);

    if (ws_size >= need_csr) {
        const int nscan = (N_NODES + 1023) / 1024;      // 49
        hipMemsetAsync(deg, 0, N_NODES * sizeof(int), stream);
        hist_k<<<(N_EDGES + 255) / 256, 256, 0, stream>>>(dst, deg);
        scan_blocks_k<<<nscan, 256, 0, stream>>>(deg, blocksums);
        scan_add_k<<<nscan, 256, 0, stream>>>(deg, blocksums, nscan);
        fill_k<<<(N_EDGES + 255) / 256, 256, 0, stream>>>(src, dst, deg, edge_src);
        aggregate_k<<<(N_NODES + 3) / 4, 256, 0, stream>>>(h, deg, edge_src, nbuf);
    } else {
        hipMemsetAsync(nbuf, 0, HN * sizeof(float), stream);
        scatter_k<<<(N_EDGES * 32) / 256, 256, 0, stream>>>(h, src, dst, nbuf);
    }

    gemm_relu_k<1><<<gblocks, 256, 0, stream>>>(h, nbuf, eps, W_phy, b_phy, out);
}

// Round 3
// 227.404 us; speedup vs baseline: 5.4959x; 1.3678x over previous
//
#include <hip/hip_runtime.h>

#define N_NODES 50000
#define N_EDGES 625000
#define DIM 128

typedef __bf16 bf16x8 __attribute__((ext_vector_type(8)));
typedef __bf16 bf16x4 __attribute__((ext_vector_type(4)));
typedef float f32x4 __attribute__((ext_vector_type(4)));

__device__ __forceinline__ float bflo(unsigned u) { return __uint_as_float(u << 16); }
__device__ __forceinline__ float bfhi(unsigned u) { return __uint_as_float(u & 0xffff0000u); }

// ===========================================================================
// MFMA GEMM + bias + relu:  out[i][j] = relu(sum_k a[i][k] * W[j][k] + b[j])
// FUSE=0: a = feats (fp32), out = h (bf16)
// FUSE=1: a = 1 + eps*h(bf16) + nbuf(fp32), out = final (fp32)
// Block: 256 thr = 4 waves; tile 64 rows x 128 cols; 16x16x32 bf16 MFMA.
// W staged fp32->bf16 in LDS [n][k], stride 136 (2-way max conflicts = free).
// A-fragments read direct from global (lane l: row m0+(l&15), k=(l>>4)*8..+7).
// Epilogue: acc -> LDS (reuse W buffer) -> coalesced vector stores.
// ===========================================================================
template <int FUSE>
__global__ __launch_bounds__(256) void gemm_mfma_k(
    const float* __restrict__ A_f32,
    const __bf16* __restrict__ A_bf16,
    const float* __restrict__ nbuf,
    const float* __restrict__ eps_p,
    const float* __restrict__ W,
    const float* __restrict__ bias,
    __bf16* __restrict__ out_bf16,
    float* __restrict__ out_f32)
{
    __shared__ __align__(16) __bf16 w_lds[128 * 136];   // 34.8 KB

    const int t = threadIdx.x;

    // Stage W: fp32 -> bf16, [n][k] stride 136
    for (int i = t; i < 4096; i += 256) {
        float4 f = ((const float4*)W)[i];
        int n = i >> 5;
        int k = (i & 31) << 2;
        __bf16* p = &w_lds[n * 136 + k];
        p[0] = (__bf16)f.x; p[1] = (__bf16)f.y;
        p[2] = (__bf16)f.z; p[3] = (__bf16)f.w;
    }
    __syncthreads();

    const int wave = t >> 6;
    const int lane = t & 63;
    const int q = lane >> 4;       // quad: k-offset q*8
    const int mr = lane & 15;      // A row within tile / B col within ntile

    const int m0 = blockIdx.x * 64 + wave * 16;
    int arow = m0 + mr;
    if (arow >= N_NODES) arow = N_NODES - 1;   // clamp (epilogue masks)

    const float eps = FUSE ? eps_p[0] : 0.0f;

    f32x4 acc[8] = {};

#pragma unroll
    for (int ks = 0; ks < 4; ++ks) {
        const int k0 = ks * 32 + q * 8;
        bf16x8 af;
        if (!FUSE) {
            const float4* ap = (const float4*)&A_f32[(size_t)arow * DIM + k0];
            float4 a0 = ap[0], a1 = ap[1];
            af[0] = (__bf16)a0.x; af[1] = (__bf16)a0.y;
            af[2] = (__bf16)a0.z; af[3] = (__bf16)a0.w;
            af[4] = (__bf16)a1.x; af[5] = (__bf16)a1.y;
            af[6] = (__bf16)a1.z; af[7] = (__bf16)a1.w;
        } else {
            uint4 hraw = *(const uint4*)&A_bf16[(size_t)arow * DIM + k0];
            const float4* np_ = (const float4*)&nbuf[(size_t)arow * DIM + k0];
            float4 n0 = np_[0], n1 = np_[1];
            float hf[8] = { bflo(hraw.x), bfhi(hraw.x), bflo(hraw.y), bfhi(hraw.y),
                            bflo(hraw.z), bfhi(hraw.z), bflo(hraw.w), bfhi(hraw.w) };
            float nf[8] = { n0.x, n0.y, n0.z, n0.w, n1.x, n1.y, n1.z, n1.w };
#pragma unroll
            for (int j = 0; j < 8; ++j)
                af[j] = (__bf16)(1.0f + eps * hf[j] + nf[j]);
        }
#pragma unroll
        for (int nt = 0; nt < 8; ++nt) {
            bf16x8 bfr = *(const bf16x8*)&w_lds[(nt * 16 + mr) * 136 + k0];
            acc[nt] = __builtin_amdgcn_mfma_f32_16x16x32_bf16(af, bfr, acc[nt], 0, 0, 0);
        }
    }

    // Epilogue: C layout col=lane&15, row=(lane>>4)*4+reg  ->  LDS -> coalesced
    __syncthreads();                       // everyone done reading w_lds
    float* lds_f = (float*)w_lds;          // 64 x 132 fp32 = 33.8 KB
#pragma unroll
    for (int nt = 0; nt < 8; ++nt)
#pragma unroll
        for (int r = 0; r < 4; ++r)
            lds_f[(wave * 16 + q * 4 + r) * 132 + nt * 16 + mr] = acc[nt][r];
    __syncthreads();

    const int nb = blockIdx.x * 64;
    for (int i = t; i < 2048; i += 256) {
        int lr = i >> 5;
        int cg = (i & 31) << 2;
        int grow = nb + lr;
        if (grow >= N_NODES) continue;
        float4 v = *(const float4*)&lds_f[lr * 132 + cg];
        float4 b4 = *(const float4*)&bias[cg];
        v.x = fmaxf(v.x + b4.x, 0.f);
        v.y = fmaxf(v.y + b4.y, 0.f);
        v.z = fmaxf(v.z + b4.z, 0.f);
        v.w = fmaxf(v.w + b4.w, 0.f);
        if (!FUSE) {
            bf16x4 o = { (__bf16)v.x, (__bf16)v.y, (__bf16)v.z, (__bf16)v.w };
            *(bf16x4*)&out_bf16[(size_t)grow * DIM + cg] = o;
        } else {
            *(float4*)&out_f32[(size_t)grow * DIM + cg] = v;
        }
    }
}

// ===========================================================================
// CSR build: histogram -> exclusive scan -> fill (offsets become segment ends)
// ===========================================================================
__global__ __launch_bounds__(256) void hist_k(
    const int* __restrict__ dst, int* __restrict__ deg)
{
    int e = blockIdx.x * 256 + threadIdx.x;
    if (e < N_EDGES) atomicAdd(&deg[dst[e]], 1);
}

__global__ __launch_bounds__(256) void scan_blocks_k(
    int* __restrict__ deg, int* __restrict__ blocksums)
{
    __shared__ int s[256];
    const int t = threadIdx.x;
    const int base = blockIdx.x * 1024 + t * 4;

    int v[4] = {0, 0, 0, 0};
    if (base + 3 < N_NODES) {
        int4 qd = *(const int4*)&deg[base];
        v[0] = qd.x; v[1] = qd.y; v[2] = qd.z; v[3] = qd.w;
    } else {
#pragma unroll
        for (int j = 0; j < 4; ++j)
            if (base + j < N_NODES) v[j] = deg[base + j];
    }
    int sum = v[0] + v[1] + v[2] + v[3];
    s[t] = sum;
    __syncthreads();
    for (int off = 1; off < 256; off <<= 1) {
        int x = (t >= off) ? s[t - off] : 0;
        __syncthreads();
        s[t] += x;
        __syncthreads();
    }
    if (t == 255) blocksums[blockIdx.x] = s[255];
    int run = s[t] - sum;
#pragma unroll
    for (int j = 0; j < 4; ++j) {
        int ex = run;
        run += v[j];
        if (base + j < N_NODES) deg[base + j] = ex;
    }
}

__global__ __launch_bounds__(256) void scan_add_k(
    int* __restrict__ deg, const int* __restrict__ blocksums, int nblocks)
{
    __shared__ int carry_s;
    const int t = threadIdx.x;
    if (t < 64) {
        int v = (t < blockIdx.x && t < nblocks) ? blocksums[t] : 0;
#pragma unroll
        for (int off = 32; off > 0; off >>= 1) v += __shfl_down(v, off, 64);
        if (t == 0) carry_s = v;
    }
    __syncthreads();
    const int carry = carry_s;
    if (carry == 0) return;
    const int base = blockIdx.x * 1024 + t * 4;
#pragma unroll
    for (int j = 0; j < 4; ++j)
        if (base + j < N_NODES) deg[base + j] += carry;
}

__global__ __launch_bounds__(256) void fill_k(
    const int* __restrict__ src, const int* __restrict__ dst,
    int* __restrict__ deg, int* __restrict__ edge_src)
{
    int e = blockIdx.x * 256 + threadIdx.x;
    if (e < N_EDGES) {
        int d = dst[e];
        int p = atomicAdd(&deg[d], 1);
        edge_src[p] = src[e];
    }
}

// ===========================================================================
// Aggregate: one wave per node; half-wave (32 lanes x 4 bf16 ch) per edge,
// two edges in flight; fp32 accumulate; cross-half shfl; one write per node.
// ===========================================================================
__global__ __launch_bounds__(256) void aggregate_k(
    const __bf16* __restrict__ h, const int* __restrict__ deg,
    const int* __restrict__ edge_src, float* __restrict__ nbuf)
{
    const int t = threadIdx.x;
    const int node = blockIdx.x * 4 + (t >> 6);
    if (node >= N_NODES) return;
    const int lane = t & 63;
    const int half = lane >> 5;
    const int cl = lane & 31;

    const int start = node ? deg[node - 1] : 0;
    const int end = deg[node];

    float4 acc = make_float4(0.f, 0.f, 0.f, 0.f);
    for (int ei = start + half; ei < end; ei += 2) {
        int s = edge_src[ei];
        uint2 rawv = *(const uint2*)&h[(size_t)s * DIM + (cl << 2)];
        acc.x += bflo(rawv.x); acc.y += bfhi(rawv.x);
        acc.z += bflo(rawv.y); acc.w += bfhi(rawv.y);
    }
    acc.x += __shfl_down(acc.x, 32, 64);
    acc.y += __shfl_down(acc.y, 32, 64);
    acc.z += __shfl_down(acc.z, 32, 64);
    acc.w += __shfl_down(acc.w, 32, 64);
    if (half == 0)
        *(float4*)&nbuf[(size_t)node * DIM + (cl << 2)] = acc;
}

extern "C" void kernel_launch(void* const* d_in, const int* in_sizes, int n_in,
                              void* d_out, int out_size, void* d_ws, size_t ws_size,
                              hipStream_t stream) {
    const float* feats = (const float*)d_in[0];
    const int*   src   = (const int*)d_in[1];
    const int*   dst   = (const int*)d_in[2];
    const float* W_f   = (const float*)d_in[3];
    const float* b_f   = (const float*)d_in[4];
    const float* W_phy = (const float*)d_in[5];
    const float* b_phy = (const float*)d_in[6];
    const float* eps   = (const float*)d_in[7];
    float* out = (float*)d_out;

    const size_t HN = (size_t)N_NODES * DIM;
    __bf16* h   = (__bf16*)d_ws;                        // 12.8 MB
    float* nbuf = (float*)(h + HN);                     // 25.6 MB
    int* edge_src = (int*)(nbuf + HN);                  // 2.5 MB
    int* deg      = edge_src + N_EDGES;                 // 200 KB
    int* blocksums = deg + N_NODES;                     // 196 B

    const int gblocks = (N_NODES + 63) / 64;            // 782
    const int nscan = (N_NODES + 1023) / 1024;          // 49

    gemm_mfma_k<0><<<gblocks, 256, 0, stream>>>(
        feats, nullptr, nullptr, nullptr, W_f, b_f, h, nullptr);

    hipMemsetAsync(deg, 0, N_NODES * sizeof(int), stream);
    hist_k<<<(N_EDGES + 255) / 256, 256, 0, stream>>>(dst, deg);
    scan_blocks_k<<<nscan, 256, 0, stream>>>(deg, blocksums);
    scan_add_k<<<nscan, 256, 0, stream>>>(deg, blocksums, nscan);
    fill_k<<<(N_EDGES + 255) / 256, 256, 0, stream>>>(src, dst, deg, edge_src);
    aggregate_k<<<(N_NODES + 3) / 4, 256, 0, stream>>>(h, deg, edge_src, nbuf);

    gemm_mfma_k<1><<<gblocks, 256, 0, stream>>>(
        nullptr, h, nbuf, eps, W_phy, b_phy, nullptr, out);
}